// Round 1
// baseline (397.519 us; speedup 1.0000x reference)
//
#include <hip/hip_runtime.h>
#include <hip/hip_cooperative_groups.h>

namespace cg = cooperative_groups;

// Problem constants (fixed by the reference)
constexpr int L    = 8192;   // vector_length
constexpr int B    = 4096;   // batch (columns)
constexpr int RANK = 8;

// Tiling: grid = CB col-blocks x NCHUNK l-chunks = 512 blocks (2 blocks/CU,
// co-resident -> cooperative grid sync is valid)
constexpr int CB      = 4;            // column blocks of 1024 cols (256 thr x float4)
constexpr int NCHUNK  = 128;          // l-chunks
constexpr int LPC     = L / NCHUNK;   // 64 l-values per chunk
constexpr int COLS_PB = 1024;
constexpr int UNROLL  = 8;
constexpr int NBLK    = CB * NCHUNK;  // 512

// ---------------------------------------------------------------------------
// Fused: phaseA (V^T partials) -> grid.sync -> phaseB (reduce to T) ->
//        grid.sync -> phaseC (U * T -> out)
// ---------------------------------------------------------------------------
__global__ __launch_bounds__(256, 2) void lr_fused(const float* __restrict__ in,
                                                   const float* __restrict__ U,
                                                   const float* __restrict__ V,
                                                   float* __restrict__ part,
                                                   float* __restrict__ T,
                                                   float* __restrict__ out) {
    const int tid = threadIdx.x;
    const int bid = blockIdx.x;
    const int cb  = bid % CB;              // column block 0..3
    const int lc  = bid / CB;              // l-chunk 0..127
    const int col = cb * COLS_PB + tid * 4;

    __shared__ float  sv[RANK][LPC];       // 2 KiB: V-slice (A), U-slice (C)
    __shared__ float4 red[4][16];          // 1 KiB: cross-wave reduce (B)

    // ---------------- Phase A: part[lc][r][b] = sum_{l in chunk} V[r][l]*in[l][b]
    {
        const int l0 = lc * LPC;
        for (int i = tid; i < RANK * LPC; i += 256) {
            const int r  = i / LPC;
            const int ll = i % LPC;
            sv[r][ll] = V[r * L + l0 + ll];
        }
        __syncthreads();

        float4 acc[RANK];
#pragma unroll
        for (int r = 0; r < RANK; ++r) acc[r] = make_float4(0.f, 0.f, 0.f, 0.f);

        const float* base = in + (size_t)l0 * B + col;
        for (int li = 0; li < LPC; li += UNROLL) {
            float4 x[UNROLL];
#pragma unroll
            for (int j = 0; j < UNROLL; ++j)
                x[j] = *(const float4*)(base + (size_t)(li + j) * B);
#pragma unroll
            for (int j = 0; j < UNROLL; ++j) {
#pragma unroll
                for (int r = 0; r < RANK; ++r) {
                    const float v = sv[r][li + j];
                    acc[r].x += v * x[j].x;
                    acc[r].y += v * x[j].y;
                    acc[r].z += v * x[j].z;
                    acc[r].w += v * x[j].w;
                }
            }
        }

        float* p = part + (size_t)lc * (RANK * B);
#pragma unroll
        for (int r = 0; r < RANK; ++r) {
            *(float4*)(p + r * B + col) = acc[r];
        }
    }

    cg::this_grid().sync();

    // ---------------- Phase B: T[i] = sum_c part[c][i], distributed over all
    // 512 blocks. T has RANK*B/4 = 8192 float4 elements -> 16 per block.
    // Within a block: wave w sums chunks [w*32, w*32+32); within a wave:
    // lane = sub*16 + e, sub sums 8 chunks, butterfly over sub (xor 16,32).
    {
        const int lane = tid & 63;
        const int w    = tid >> 6;                 // wave 0..3
        const int e    = bid * 16 + (lane & 15);   // float4 index into T
        const int sub  = lane >> 4;                // 0..3
        const int c0   = w * 32 + sub * 8;
        const float4* p4 = (const float4*)part;

        float4 s = make_float4(0.f, 0.f, 0.f, 0.f);
#pragma unroll
        for (int k = 0; k < 8; ++k) {
            const float4 v = p4[(size_t)(c0 + k) * (RANK * B / 4) + e];
            s.x += v.x; s.y += v.y; s.z += v.z; s.w += v.w;
        }
#pragma unroll
        for (int m = 16; m < 64; m <<= 1) {
            s.x += __shfl_xor(s.x, m, 64);
            s.y += __shfl_xor(s.y, m, 64);
            s.z += __shfl_xor(s.z, m, 64);
            s.w += __shfl_xor(s.w, m, 64);
        }
        if (lane < 16) red[w][lane] = s;
        __syncthreads();
        if (w == 0 && lane < 16) {
            const float4 a = red[0][lane];
            const float4 b = red[1][lane];
            const float4 c = red[2][lane];
            const float4 d = red[3][lane];
            float4 t;
            t.x = (a.x + b.x) + (c.x + d.x);
            t.y = (a.y + b.y) + (c.y + d.y);
            t.z = (a.z + b.z) + (c.z + d.z);
            t.w = (a.w + b.w) + (c.w + d.w);
            ((float4*)T)[bid * 16 + lane] = t;
        }
    }

    cg::this_grid().sync();

    // ---------------- Phase C: out[l][b] = sum_r U[r][l] * T[r][b]
    // Same (cb, lc) partition as phase A: 64 rows x 1024 cols per block.
    {
        const int l0 = lc * LPC;
        for (int i = tid; i < RANK * LPC; i += 256) {
            const int r  = i / LPC;
            const int ll = i % LPC;
            sv[r][ll] = U[r * L + l0 + ll];
        }
        __syncthreads();

        float4 t[RANK];
#pragma unroll
        for (int r = 0; r < RANK; ++r) t[r] = *(const float4*)(T + r * B + col);

        for (int li = 0; li < LPC; ++li) {
            float4 o = make_float4(0.f, 0.f, 0.f, 0.f);
#pragma unroll
            for (int r = 0; r < RANK; ++r) {
                const float u = sv[r][li];
                o.x += u * t[r].x;
                o.y += u * t[r].y;
                o.z += u * t[r].z;
                o.w += u * t[r].w;
            }
            *(float4*)(out + (size_t)(l0 + li) * B + col) = o;
        }
    }
}

// ---------------------------------------------------------------------------
extern "C" void kernel_launch(void* const* d_in, const int* in_sizes, int n_in,
                              void* d_out, int out_size, void* d_ws, size_t ws_size,
                              hipStream_t stream) {
    const float* in = (const float*)d_in[0];   // [L, B]
    const float* U  = (const float*)d_in[1];   // [RANK, L]
    const float* V  = (const float*)d_in[2];   // [RANK, L]
    float* out = (float*)d_out;                // [L, B]

    // ws layout: partials (NCHUNK * RANK * B floats = 16 MiB) then T (RANK*B)
    float* part = (float*)d_ws;
    float* T    = part + (size_t)NCHUNK * RANK * B;

    void* args[6] = {(void*)&in, (void*)&U, (void*)&V,
                     (void*)&part, (void*)&T, (void*)&out};
    hipLaunchCooperativeKernel((void*)lr_fused, dim3(NBLK), dim3(256),
                               args, 0, stream);
}

// Round 3
// 243.116 us; speedup vs baseline: 1.6351x; 1.6351x over previous
//
#include <hip/hip_runtime.h>

// Problem constants (fixed by the reference)
constexpr int L    = 8192;   // vector_length
constexpr int B    = 4096;   // batch (columns)
constexpr int RANK = 8;

// Pass-1 tiling: grid = CB col-blocks x NCHUNK l-chunks
constexpr int CB      = 4;            // column blocks of 1024 cols (256 thr x float4)
constexpr int NCHUNK  = 128;          // l-chunks  -> 512 blocks = 2 blocks/CU
constexpr int LPC     = L / NCHUNK;   // 64 l-values per chunk
constexpr int COLS_PB = 1024;
constexpr int UNROLL  = 8;

// Pass-2 tiling
constexpr int LPB = 16;               // l-rows per block -> 2048 blocks = 8/CU

// Native vector type acceptable to __builtin_nontemporal_{load,store}
typedef float nfloat4 __attribute__((ext_vector_type(4)));

// ---------------------------------------------------------------------------
// pass1: partial T: part[lc][r][b] = sum_{l in chunk lc} V[r][l] * in[l][b]
// (unchanged from the 250.7 µs baseline — proven ~25-35 µs)
// ---------------------------------------------------------------------------
__global__ __launch_bounds__(256) void lr_pass1(const float* __restrict__ in,
                                                const float* __restrict__ V,
                                                float* __restrict__ part) {
    const int cb  = blockIdx.x % CB;
    const int lc  = blockIdx.x / CB;
    const int col = cb * COLS_PB + threadIdx.x * 4;
    const int l0  = lc * LPC;

    __shared__ float vs[RANK][LPC];     // 2 KiB
    for (int i = threadIdx.x; i < RANK * LPC; i += 256) {
        const int r  = i / LPC;
        const int ll = i % LPC;
        vs[r][ll] = V[r * L + l0 + ll];
    }
    __syncthreads();

    float4 acc[RANK];
#pragma unroll
    for (int r = 0; r < RANK; ++r) acc[r] = make_float4(0.f, 0.f, 0.f, 0.f);

    const float* base = in + (size_t)l0 * B + col;
    for (int li = 0; li < LPC; li += UNROLL) {
        float4 x[UNROLL];
#pragma unroll
        for (int j = 0; j < UNROLL; ++j)
            x[j] = *(const float4*)(base + (size_t)(li + j) * B);
#pragma unroll
        for (int j = 0; j < UNROLL; ++j) {
#pragma unroll
            for (int r = 0; r < RANK; ++r) {
                const float v = vs[r][li + j];
                acc[r].x += v * x[j].x;
                acc[r].y += v * x[j].y;
                acc[r].z += v * x[j].z;
                acc[r].w += v * x[j].w;
            }
        }
    }

    float* p = part + (size_t)lc * (RANK * B);
#pragma unroll
    for (int r = 0; r < RANK; ++r) {
        *(float4*)(p + r * B + col) = acc[r];
    }
}

// ---------------------------------------------------------------------------
// reduce: T[i] = sum_c part[c][i]  — distributed over 512 blocks (2/CU).
// Block handles 16 float4 of T. Wave w sums chunks [w*32,(w+1)*32):
//   lane = sub*16 + e; sub accumulates 8 chunks; butterfly xor{16,32}
//   folds the 4 subs; LDS folds the 4 waves.
// part loads are nontemporal (dead after this kernel).
// ---------------------------------------------------------------------------
__global__ __launch_bounds__(256) void lr_reduce(const float* __restrict__ part,
                                                 float* __restrict__ T) {
    const int tid  = threadIdx.x;
    const int bid  = blockIdx.x;
    const int lane = tid & 63;
    const int w    = tid >> 6;                 // wave 0..3
    const int e    = bid * 16 + (lane & 15);   // float4 index into T
    const int sub  = lane >> 4;                // 0..3
    const int c0   = w * 32 + sub * 8;
    const nfloat4* p4 = (const nfloat4*)part;

    __shared__ float4 red[4][16];

    nfloat4 s = {0.f, 0.f, 0.f, 0.f};
#pragma unroll
    for (int k = 0; k < 8; ++k) {
        const nfloat4 v =
            __builtin_nontemporal_load(&p4[(size_t)(c0 + k) * (RANK * B / 4) + e]);
        s += v;
    }
    float4 sv = make_float4(s.x, s.y, s.z, s.w);
#pragma unroll
    for (int m = 16; m < 64; m <<= 1) {
        sv.x += __shfl_xor(sv.x, m, 64);
        sv.y += __shfl_xor(sv.y, m, 64);
        sv.z += __shfl_xor(sv.z, m, 64);
        sv.w += __shfl_xor(sv.w, m, 64);
    }
    if (lane < 16) red[w][lane] = sv;
    __syncthreads();
    if (w == 0 && lane < 16) {
        const float4 a = red[0][lane];
        const float4 b = red[1][lane];
        const float4 c = red[2][lane];
        const float4 d = red[3][lane];
        float4 t;
        t.x = (a.x + b.x) + (c.x + d.x);
        t.y = (a.y + b.y) + (c.y + d.y);
        t.z = (a.z + b.z) + (c.z + d.z);
        t.w = (a.w + b.w) + (c.w + d.w);
        ((float4*)T)[bid * 16 + lane] = t;
    }
}

// ---------------------------------------------------------------------------
// pass2: out[l][b] = sum_r U[r][l] * T[r][b]
// out stores are nontemporal: never re-read, keep L2 for in/T.
// ---------------------------------------------------------------------------
__global__ __launch_bounds__(256) void lr_pass2(const float* __restrict__ T,
                                                const float* __restrict__ U,
                                                float* __restrict__ out) {
    const int cb  = blockIdx.x % CB;
    const int lb  = blockIdx.x / CB;
    const int col = cb * COLS_PB + threadIdx.x * 4;
    const int l0  = lb * LPB;

    __shared__ float us[RANK][LPB];     // 512 B
    if (threadIdx.x < RANK * LPB) {
        const int r  = threadIdx.x / LPB;
        const int ll = threadIdx.x % LPB;
        us[r][ll] = U[r * L + l0 + ll];
    }
    __syncthreads();

    float4 t[RANK];
#pragma unroll
    for (int r = 0; r < RANK; ++r) t[r] = *(const float4*)(T + r * B + col);

#pragma unroll
    for (int li = 0; li < LPB; ++li) {
        nfloat4 o = {0.f, 0.f, 0.f, 0.f};
#pragma unroll
        for (int r = 0; r < RANK; ++r) {
            const float u = us[r][li];
            o.x += u * t[r].x;
            o.y += u * t[r].y;
            o.z += u * t[r].z;
            o.w += u * t[r].w;
        }
        __builtin_nontemporal_store(o, (nfloat4*)(out + (size_t)(l0 + li) * B + col));
    }
}

// ---------------------------------------------------------------------------
extern "C" void kernel_launch(void* const* d_in, const int* in_sizes, int n_in,
                              void* d_out, int out_size, void* d_ws, size_t ws_size,
                              hipStream_t stream) {
    const float* in = (const float*)d_in[0];   // [L, B]
    const float* U  = (const float*)d_in[1];   // [RANK, L]
    const float* V  = (const float*)d_in[2];   // [RANK, L]
    float* out = (float*)d_out;                // [L, B]

    // ws layout: partials (NCHUNK * RANK * B floats = 16 MiB) then T (RANK*B)
    float* part = (float*)d_ws;
    float* T    = part + (size_t)NCHUNK * RANK * B;

    lr_pass1 <<<CB * NCHUNK,    256, 0, stream>>>(in, V, part);
    lr_reduce<<<(RANK * B) / (16 * 4), 256, 0, stream>>>(part, T);   // 512 blocks
    lr_pass2 <<<CB * (L / LPB), 256, 0, stream>>>(T, U, out);
}

// Round 4
// 241.725 us; speedup vs baseline: 1.6445x; 1.0058x over previous
//
#include <hip/hip_runtime.h>

// Problem constants (fixed by the reference)
constexpr int L    = 8192;   // vector_length
constexpr int B    = 4096;   // batch (columns)
constexpr int RANK = 8;

// Pass-1 tiling: 32 l-chunks of 256 rows x 16 col-stripes of 256 cols
//   = 512 blocks (2/CU). Each of the 4 waves covers a disjoint 64-row
//   group; an LDS fold merges them so only ONE partial per chunk hits HBM
//   (part shrinks 16.8 MB -> 4.2 MB vs the NCHUNK=128 layout).
constexpr int NCHUNK  = 32;
constexpr int ROWS_PC = L / NCHUNK;     // 256 rows per chunk
constexpr int CSTRIPE = 16;             // col stripes
constexpr int COLS_PS = B / CSTRIPE;    // 256 cols per stripe (64 lanes x float4)
constexpr int UNROLL  = 8;

// Pass-2 tiling
constexpr int CB      = 4;
constexpr int COLS_PB = 1024;
constexpr int LPB     = 16;             // l-rows per block -> 2048 blocks

// Native vector type acceptable to __builtin_nontemporal_{load,store}
typedef float nfloat4 __attribute__((ext_vector_type(4)));

// ---------------------------------------------------------------------------
// pass1: part[lc][r][b] = sum_{l in chunk lc} V[r][l] * in[l][b]
// wave w handles rows [lc*256 + w*64, +64); LDS fold merges 4 waves.
// ---------------------------------------------------------------------------
__global__ __launch_bounds__(256) void lr_pass1(const float* __restrict__ in,
                                                const float* __restrict__ V,
                                                float* __restrict__ part) {
    const int cs   = blockIdx.x % CSTRIPE;
    const int lc   = blockIdx.x / CSTRIPE;
    const int lane = threadIdx.x & 63;
    const int w    = threadIdx.x >> 6;          // wave 0..3
    const int col  = cs * COLS_PS + lane * 4;
    const int l0   = lc * ROWS_PC;

    __shared__ float  vs[RANK][ROWS_PC];        // 8 KiB: V slice for the chunk
    __shared__ float4 fold[3][64][RANK];        // 24 KiB: waves 1-3 partials

    for (int i = threadIdx.x; i < RANK * ROWS_PC; i += 256) {
        const int r  = i / ROWS_PC;
        const int ll = i % ROWS_PC;
        vs[r][ll] = V[r * L + l0 + ll];
    }
    __syncthreads();

    float4 acc[RANK];
#pragma unroll
    for (int r = 0; r < RANK; ++r) acc[r] = make_float4(0.f, 0.f, 0.f, 0.f);

    const float* base = in + (size_t)(l0 + w * 64) * B + col;
    for (int li = 0; li < 64; li += UNROLL) {
        float4 x[UNROLL];
#pragma unroll
        for (int j = 0; j < UNROLL; ++j)
            x[j] = *(const float4*)(base + (size_t)(li + j) * B);
#pragma unroll
        for (int j = 0; j < UNROLL; ++j) {
#pragma unroll
            for (int r = 0; r < RANK; ++r) {
                const float v = vs[r][w * 64 + li + j];
                acc[r].x += v * x[j].x;
                acc[r].y += v * x[j].y;
                acc[r].z += v * x[j].z;
                acc[r].w += v * x[j].w;
            }
        }
    }

    if (w > 0) {
#pragma unroll
        for (int r = 0; r < RANK; ++r) fold[w - 1][lane][r] = acc[r];
    }
    __syncthreads();

    if (w == 0) {
        float* p = part + (size_t)lc * (RANK * B);
#pragma unroll
        for (int r = 0; r < RANK; ++r) {
            const float4 a = fold[0][lane][r];
            const float4 b = fold[1][lane][r];
            const float4 c = fold[2][lane][r];
            nfloat4 o;
            o.x = acc[r].x + ((a.x + b.x) + c.x);
            o.y = acc[r].y + ((a.y + b.y) + c.y);
            o.z = acc[r].z + ((a.z + b.z) + c.z);
            o.w = acc[r].w + ((a.w + b.w) + c.w);
            __builtin_nontemporal_store(o, (nfloat4*)(p + r * B + col));
        }
    }
}

// ---------------------------------------------------------------------------
// reduce: T[i] = sum_{c<32} part[c][i] — 512 blocks (2/CU), 16 float4 each.
// wave w sums chunks [w*8,(w+1)*8): lane = sub*16+e, sub sums 2 chunks;
// butterfly xor{16,32} folds subs; LDS folds the 4 waves.
// ---------------------------------------------------------------------------
__global__ __launch_bounds__(256) void lr_reduce(const float* __restrict__ part,
                                                 float* __restrict__ T) {
    const int tid  = threadIdx.x;
    const int bid  = blockIdx.x;
    const int lane = tid & 63;
    const int w    = tid >> 6;                 // wave 0..3
    const int e    = bid * 16 + (lane & 15);   // float4 index into T
    const int sub  = lane >> 4;                // 0..3
    const int c0   = w * 8 + sub * 2;
    const nfloat4* p4 = (const nfloat4*)part;

    __shared__ float4 red[4][16];

    nfloat4 s = {0.f, 0.f, 0.f, 0.f};
#pragma unroll
    for (int k = 0; k < 2; ++k) {
        const nfloat4 v =
            __builtin_nontemporal_load(&p4[(size_t)(c0 + k) * (RANK * B / 4) + e]);
        s += v;
    }
    float4 sv = make_float4(s.x, s.y, s.z, s.w);
#pragma unroll
    for (int m = 16; m < 64; m <<= 1) {
        sv.x += __shfl_xor(sv.x, m, 64);
        sv.y += __shfl_xor(sv.y, m, 64);
        sv.z += __shfl_xor(sv.z, m, 64);
        sv.w += __shfl_xor(sv.w, m, 64);
    }
    if (lane < 16) red[w][lane] = sv;
    __syncthreads();
    if (w == 0 && lane < 16) {
        const float4 a = red[0][lane];
        const float4 b = red[1][lane];
        const float4 c = red[2][lane];
        const float4 d = red[3][lane];
        float4 t;
        t.x = (a.x + b.x) + (c.x + d.x);
        t.y = (a.y + b.y) + (c.y + d.y);
        t.z = (a.z + b.z) + (c.z + d.z);
        t.w = (a.w + b.w) + (c.w + d.w);
        ((float4*)T)[bid * 16 + lane] = t;
    }
}

// ---------------------------------------------------------------------------
// pass2: out[l][b] = sum_r U[r][l] * T[r][b]
// out stores nontemporal: never re-read, keep L2 for in/T.
// ---------------------------------------------------------------------------
__global__ __launch_bounds__(256) void lr_pass2(const float* __restrict__ T,
                                                const float* __restrict__ U,
                                                float* __restrict__ out) {
    const int cb  = blockIdx.x % CB;
    const int lb  = blockIdx.x / CB;
    const int col = cb * COLS_PB + threadIdx.x * 4;
    const int l0  = lb * LPB;

    __shared__ float us[RANK][LPB];     // 512 B
    if (threadIdx.x < RANK * LPB) {
        const int r  = threadIdx.x / LPB;
        const int ll = threadIdx.x % LPB;
        us[r][ll] = U[r * L + l0 + ll];
    }
    __syncthreads();

    float4 t[RANK];
#pragma unroll
    for (int r = 0; r < RANK; ++r) t[r] = *(const float4*)(T + r * B + col);

#pragma unroll
    for (int li = 0; li < LPB; ++li) {
        nfloat4 o = {0.f, 0.f, 0.f, 0.f};
#pragma unroll
        for (int r = 0; r < RANK; ++r) {
            const float u = us[r][li];
            o.x += u * t[r].x;
            o.y += u * t[r].y;
            o.z += u * t[r].z;
            o.w += u * t[r].w;
        }
        __builtin_nontemporal_store(o, (nfloat4*)(out + (size_t)(l0 + li) * B + col));
    }
}

// ---------------------------------------------------------------------------
extern "C" void kernel_launch(void* const* d_in, const int* in_sizes, int n_in,
                              void* d_out, int out_size, void* d_ws, size_t ws_size,
                              hipStream_t stream) {
    const float* in = (const float*)d_in[0];   // [L, B]
    const float* U  = (const float*)d_in[1];   // [RANK, L]
    const float* V  = (const float*)d_in[2];   // [RANK, L]
    float* out = (float*)d_out;                // [L, B]

    // ws layout: partials (NCHUNK * RANK * B floats = 4 MiB) then T (RANK*B)
    float* part = (float*)d_ws;
    float* T    = part + (size_t)NCHUNK * RANK * B;

    lr_pass1 <<<CSTRIPE * NCHUNK,      256, 0, stream>>>(in, V, part);
    lr_reduce<<<(RANK * B) / (16 * 4), 256, 0, stream>>>(part, T);   // 512 blocks
    lr_pass2 <<<CB * (L / LPB),        256, 0, stream>>>(T, U, out);
}